// Round 2
// baseline (629.670 us; speedup 1.0000x reference)
//
#include <hip/hip_runtime.h>
#include <hip/hip_bf16.h>

// B=16, S=4096, H=512 ; G=2, V=320, D=256 (Dg = D/G = 128)
constexpr int BT = 16 * 4096;   // 65536 rows
constexpr int K  = 512;         // H
constexpr int V  = 320;         // codes per group
constexpr int G  = 2;           // groups
constexpr int Dg = 128;         // code dim per group
constexpr int MT = 64;          // rows per block
constexpr int KB = 16;          // K panel
constexpr int HS_STRIDE = MT + 4;  // 68 floats: keeps float4 alignment (68%4==0), banks 2-way max

// Fused GEMM(64x320x512 fp32) + argmax + gather + histogram.
// Grid: (BT/MT, G). Block: 256 threads.
// Thread map: rp = tid>>4 (rows 4rp..4rp+3), cg = tid&15 (cols cg*20..cg*20+19).
__global__ __launch_bounds__(256, 4) void vq_main(
    const float* __restrict__ hs, const float* __restrict__ Wm,
    const float* __restrict__ bv, const float* __restrict__ cb,
    float* __restrict__ out, unsigned int* __restrict__ hist)
{
    __shared__ float hs_s[KB][HS_STRIDE];  // [16][68]
    __shared__ float W_s[KB][V];           // [16][320]
    __shared__ float red_v[MT][16];
    __shared__ int   red_i[MT][16];
    __shared__ int   idx_s[MT];

    const int tid = threadIdx.x;
    const int bm  = blockIdx.x;
    const int g   = blockIdx.y;
    const int r0  = bm * MT;

    const int rp  = tid >> 4;    // 0..15 -> rows 4rp..4rp+3
    const int cg  = tid & 15;    // 0..15
    const int cb0 = cg * 20;     // col base within group

    float acc0[20], acc1[20], acc2[20], acc3[20];
#pragma unroll
    for (int j = 0; j < 20; ++j) {
        float b0 = bv[g * V + cb0 + j];
        acc0[j] = b0; acc1[j] = b0; acc2[j] = b0; acc3[j] = b0;
    }

    // hs staging map: row = tid>>2 (0..63), t = tid&3 -> float4 covering k = 4t..4t+3
    const int st_row = tid >> 2;
    const int st_t   = tid & 3;

    for (int kt = 0; kt < K; kt += KB) {
        // ---- stage hs panel: 64 rows x 16 k, 1 float4 per thread, transposed store ----
        {
            float4 h4 = *reinterpret_cast<const float4*>(
                &hs[(size_t)(r0 + st_row) * K + kt + st_t * 4]);
            hs_s[st_t * 4 + 0][st_row] = h4.x;
            hs_s[st_t * 4 + 1][st_row] = h4.y;
            hs_s[st_t * 4 + 2][st_row] = h4.z;
            hs_s[st_t * 4 + 3][st_row] = h4.w;
        }
        // ---- stage W panel: 16 k x 320 cols (1280 float4, 5 per thread) ----
#pragma unroll
        for (int rep = 0; rep < 5; ++rep) {
            int idx = rep * 256 + tid;     // 0..1279
            int kk  = idx / 80;            // 80 float4 per k-row
            int c4  = idx - kk * 80;
            float4 w4 = *reinterpret_cast<const float4*>(
                &Wm[(size_t)(kt + kk) * (G * V) + g * V + c4 * 4]);
            *reinterpret_cast<float4*>(&W_s[kk][c4 * 4]) = w4;
        }
        __syncthreads();
        // ---- compute: per kk, 6 LDS reads -> 80 FMA ----
#pragma unroll 4
        for (int kk = 0; kk < KB; ++kk) {
            float4 h = *reinterpret_cast<const float4*>(&hs_s[kk][rp * 4]);
#pragma unroll
            for (int j4 = 0; j4 < 5; ++j4) {
                float4 w = *reinterpret_cast<const float4*>(&W_s[kk][cb0 + j4 * 4]);
                acc0[j4*4+0] += h.x * w.x;  acc0[j4*4+1] += h.x * w.y;
                acc0[j4*4+2] += h.x * w.z;  acc0[j4*4+3] += h.x * w.w;
                acc1[j4*4+0] += h.y * w.x;  acc1[j4*4+1] += h.y * w.y;
                acc1[j4*4+2] += h.y * w.z;  acc1[j4*4+3] += h.y * w.w;
                acc2[j4*4+0] += h.z * w.x;  acc2[j4*4+1] += h.z * w.y;
                acc2[j4*4+2] += h.z * w.z;  acc2[j4*4+3] += h.z * w.w;
                acc3[j4*4+0] += h.w * w.x;  acc3[j4*4+1] += h.w * w.y;
                acc3[j4*4+2] += h.w * w.z;  acc3[j4*4+3] += h.w * w.w;
            }
        }
        __syncthreads();
    }

    // ---- thread-local argmax per row (ascending cols, strict > => first occurrence) ----
    {
        float v0 = acc0[0], v1 = acc1[0], v2 = acc2[0], v3 = acc3[0];
        int   i0 = 0, i1 = 0, i2 = 0, i3 = 0;
#pragma unroll
        for (int j = 1; j < 20; ++j) {
            if (acc0[j] > v0) { v0 = acc0[j]; i0 = j; }
            if (acc1[j] > v1) { v1 = acc1[j]; i1 = j; }
            if (acc2[j] > v2) { v2 = acc2[j]; i2 = j; }
            if (acc3[j] > v3) { v3 = acc3[j]; i3 = j; }
        }
        red_v[rp * 4 + 0][cg] = v0;  red_i[rp * 4 + 0][cg] = cb0 + i0;
        red_v[rp * 4 + 1][cg] = v1;  red_i[rp * 4 + 1][cg] = cb0 + i1;
        red_v[rp * 4 + 2][cg] = v2;  red_i[rp * 4 + 2][cg] = cb0 + i2;
        red_v[rp * 4 + 3][cg] = v3;  red_i[rp * 4 + 3][cg] = cb0 + i3;
    }
    __syncthreads();

    // ---- per-row reduce across 16 col-groups (ascending cg => first occurrence) ----
    if (tid < MT) {
        float bvv = red_v[tid][0]; int bi = red_i[tid][0];
#pragma unroll
        for (int c = 1; c < 16; ++c) {
            if (red_v[tid][c] > bvv) { bvv = red_v[tid][c]; bi = red_i[tid][c]; }
        }
        idx_s[tid] = bi;
        atomicAdd(&hist[g * V + bi], 1u);
    }
    __syncthreads();

    // ---- gather: 64 rows x 32 float4 = 2048 float4, 8 per thread ----
#pragma unroll
    for (int rep = 0; rep < 8; ++rep) {
        int idx = rep * 256 + tid;     // 0..2047
        int row = idx >> 5;            // 32 float4 per row
        int d4  = idx & 31;
        int vi  = idx_s[row];
        float4 val = *reinterpret_cast<const float4*>(
            &cb[((size_t)(g * V + vi)) * Dg + d4 * 4]);
        *reinterpret_cast<float4*>(
            &out[((size_t)(r0 + row)) * (G * Dg) + g * Dg + d4 * 4]) = val;
    }
}

// Perplexity from histogram: one wave.
__global__ void vq_ppl(const unsigned int* __restrict__ hist, float* __restrict__ outp)
{
    int lane = threadIdx.x;  // 64
    float ppl = 0.0f;
    for (int g = 0; g < G; ++g) {
        float local = 0.0f;
        for (int v = lane; v < V; v += 64) {
            float m = (float)hist[g * V + v] * (1.0f / (float)BT);
            local += m * logf(m + 1e-7f);
        }
#pragma unroll
        for (int off = 32; off; off >>= 1) local += __shfl_down(local, off);
        if (lane == 0) ppl += expf(-local);
    }
    if (lane == 0) outp[0] = ppl;
}

extern "C" void kernel_launch(void* const* d_in, const int* in_sizes, int n_in,
                              void* d_out, int out_size, void* d_ws, size_t ws_size,
                              hipStream_t stream)
{
    const float* hs = (const float*)d_in[0];   // (B,S,H)
    const float* Wm = (const float*)d_in[1];   // (H, G*V)
    const float* bv = (const float*)d_in[2];   // (G*V,)
    const float* cb = (const float*)d_in[3];   // (1, G*V, Dg)
    float* out = (float*)d_out;                // BT*G*Dg floats, then 1 float perplexity
    unsigned int* hist = (unsigned int*)d_ws;  // G*V counters

    hipMemsetAsync(d_ws, 0, G * V * sizeof(unsigned int), stream);

    dim3 grid(BT / MT, G);
    vq_main<<<grid, 256, 0, stream>>>(hs, Wm, bv, cb, out, hist);
    vq_ppl<<<1, 64, 0, stream>>>(hist, out + (size_t)BT * G * Dg);
}

// Round 3
// 493.186 us; speedup vs baseline: 1.2767x; 1.2767x over previous
//
#include <hip/hip_runtime.h>
#include <hip/hip_bf16.h>

// B=16, S=4096, H=512 ; G=2, V=320, D=256 (Dg = D/G = 128)
constexpr int BT = 16 * 4096;   // 65536 rows
constexpr int K  = 512;         // H
constexpr int V  = 320;         // codes per group
constexpr int G  = 2;           // groups
constexpr int Dg = 128;         // code dim per group
constexpr int MT = 64;          // rows per block
constexpr int KB = 16;          // K panel
constexpr int HS_STRIDE = MT + 4;  // 68 floats: float4-aligned, 2-way banks max (free)

// Fused GEMM(64x320x512 fp32) + argmax + gather + histogram.
// Grid: (BT/MT, G). Block: 256 threads.
// Thread map: rp = tid>>4 (rows 4rp..4rp+3), cg = tid&15 (cols cg*20..cg*20+19).
// NOTE: no min-waves clamp — R2 showed __launch_bounds__(256,4) forced VGPR=64
// and spilled the 80-float accumulator tile to scratch (FETCH 142->669MB).
__global__ __launch_bounds__(256) void vq_main(
    const float* __restrict__ hs, const float* __restrict__ Wm,
    const float* __restrict__ bv, const float* __restrict__ cb,
    float* __restrict__ out, unsigned int* __restrict__ hist)
{
    __shared__ float hs_s[KB][HS_STRIDE];  // [16][68]
    __shared__ float W_s[KB][V];           // [16][320]
    __shared__ float red_v[MT][16];
    __shared__ int   red_i[MT][16];
    __shared__ int   idx_s[MT];

    const int tid = threadIdx.x;
    const int bm  = blockIdx.x;
    const int g   = blockIdx.y;
    const int r0  = bm * MT;

    const int rp  = tid >> 4;    // 0..15 -> rows 4rp..4rp+3
    const int cg  = tid & 15;    // 0..15
    const int cb0 = cg * 20;     // col base within group

    float acc0[20], acc1[20], acc2[20], acc3[20];
#pragma unroll
    for (int j = 0; j < 20; ++j) {
        float b0 = bv[g * V + cb0 + j];
        acc0[j] = b0; acc1[j] = b0; acc2[j] = b0; acc3[j] = b0;
    }

    // hs staging map: row = tid>>2 (0..63), t = tid&3 -> float4 covering k = 4t..4t+3
    const int st_row = tid >> 2;
    const int st_t   = tid & 3;

    for (int kt = 0; kt < K; kt += KB) {
        // ---- stage hs panel: 64 rows x 16 k, 1 float4 per thread, transposed store ----
        {
            float4 h4 = *reinterpret_cast<const float4*>(
                &hs[(size_t)(r0 + st_row) * K + kt + st_t * 4]);
            hs_s[st_t * 4 + 0][st_row] = h4.x;
            hs_s[st_t * 4 + 1][st_row] = h4.y;
            hs_s[st_t * 4 + 2][st_row] = h4.z;
            hs_s[st_t * 4 + 3][st_row] = h4.w;
        }
        // ---- stage W panel: 16 k x 320 cols (1280 float4, 5 per thread) ----
#pragma unroll
        for (int rep = 0; rep < 5; ++rep) {
            int idx = rep * 256 + tid;     // 0..1279
            int kk  = idx / 80;            // 80 float4 per k-row
            int c4  = idx - kk * 80;
            float4 w4 = *reinterpret_cast<const float4*>(
                &Wm[(size_t)(kt + kk) * (G * V) + g * V + c4 * 4]);
            *reinterpret_cast<float4*>(&W_s[kk][c4 * 4]) = w4;
        }
        __syncthreads();
        // ---- compute: per kk, 6 LDS b128 reads -> 80 FMA ----
        for (int kk = 0; kk < KB; ++kk) {
            float4 h = *reinterpret_cast<const float4*>(&hs_s[kk][rp * 4]);
#pragma unroll
            for (int j4 = 0; j4 < 5; ++j4) {
                float4 w = *reinterpret_cast<const float4*>(&W_s[kk][cb0 + j4 * 4]);
                acc0[j4*4+0] += h.x * w.x;  acc0[j4*4+1] += h.x * w.y;
                acc0[j4*4+2] += h.x * w.z;  acc0[j4*4+3] += h.x * w.w;
                acc1[j4*4+0] += h.y * w.x;  acc1[j4*4+1] += h.y * w.y;
                acc1[j4*4+2] += h.y * w.z;  acc1[j4*4+3] += h.y * w.w;
                acc2[j4*4+0] += h.z * w.x;  acc2[j4*4+1] += h.z * w.y;
                acc2[j4*4+2] += h.z * w.z;  acc2[j4*4+3] += h.z * w.w;
                acc3[j4*4+0] += h.w * w.x;  acc3[j4*4+1] += h.w * w.y;
                acc3[j4*4+2] += h.w * w.z;  acc3[j4*4+3] += h.w * w.w;
            }
        }
        __syncthreads();
    }

    // ---- thread-local argmax per row (ascending cols, strict > => first occurrence) ----
    {
        float v0 = acc0[0], v1 = acc1[0], v2 = acc2[0], v3 = acc3[0];
        int   i0 = 0, i1 = 0, i2 = 0, i3 = 0;
#pragma unroll
        for (int j = 1; j < 20; ++j) {
            if (acc0[j] > v0) { v0 = acc0[j]; i0 = j; }
            if (acc1[j] > v1) { v1 = acc1[j]; i1 = j; }
            if (acc2[j] > v2) { v2 = acc2[j]; i2 = j; }
            if (acc3[j] > v3) { v3 = acc3[j]; i3 = j; }
        }
        red_v[rp * 4 + 0][cg] = v0;  red_i[rp * 4 + 0][cg] = cb0 + i0;
        red_v[rp * 4 + 1][cg] = v1;  red_i[rp * 4 + 1][cg] = cb0 + i1;
        red_v[rp * 4 + 2][cg] = v2;  red_i[rp * 4 + 2][cg] = cb0 + i2;
        red_v[rp * 4 + 3][cg] = v3;  red_i[rp * 4 + 3][cg] = cb0 + i3;
    }
    __syncthreads();

    // ---- per-row reduce across 16 col-groups (ascending cg => first occurrence) ----
    if (tid < MT) {
        float bvv = red_v[tid][0]; int bi = red_i[tid][0];
#pragma unroll
        for (int c = 1; c < 16; ++c) {
            if (red_v[tid][c] > bvv) { bvv = red_v[tid][c]; bi = red_i[tid][c]; }
        }
        idx_s[tid] = bi;
        atomicAdd(&hist[g * V + bi], 1u);
    }
    __syncthreads();

    // ---- gather: 64 rows x 32 float4 = 2048 float4, 8 per thread ----
#pragma unroll
    for (int rep = 0; rep < 8; ++rep) {
        int idx = rep * 256 + tid;     // 0..2047
        int row = idx >> 5;            // 32 float4 per row
        int d4  = idx & 31;
        int vi  = idx_s[row];
        float4 val = *reinterpret_cast<const float4*>(
            &cb[((size_t)(g * V + vi)) * Dg + d4 * 4]);
        *reinterpret_cast<float4*>(
            &out[((size_t)(r0 + row)) * (G * Dg) + g * Dg + d4 * 4]) = val;
    }
}

// Perplexity from histogram: one wave.
__global__ void vq_ppl(const unsigned int* __restrict__ hist, float* __restrict__ outp)
{
    int lane = threadIdx.x;  // 64
    float ppl = 0.0f;
    for (int g = 0; g < G; ++g) {
        float local = 0.0f;
        for (int v = lane; v < V; v += 64) {
            float m = (float)hist[g * V + v] * (1.0f / (float)BT);
            local += m * logf(m + 1e-7f);
        }
#pragma unroll
        for (int off = 32; off; off >>= 1) local += __shfl_down(local, off);
        if (lane == 0) ppl += expf(-local);
    }
    if (lane == 0) outp[0] = ppl;
}

extern "C" void kernel_launch(void* const* d_in, const int* in_sizes, int n_in,
                              void* d_out, int out_size, void* d_ws, size_t ws_size,
                              hipStream_t stream)
{
    const float* hs = (const float*)d_in[0];   // (B,S,H)
    const float* Wm = (const float*)d_in[1];   // (H, G*V)
    const float* bv = (const float*)d_in[2];   // (G*V,)
    const float* cb = (const float*)d_in[3];   // (1, G*V, Dg)
    float* out = (float*)d_out;                // BT*G*Dg floats, then 1 float perplexity
    unsigned int* hist = (unsigned int*)d_ws;  // G*V counters

    hipMemsetAsync(d_ws, 0, G * V * sizeof(unsigned int), stream);

    dim3 grid(BT / MT, G);
    vq_main<<<grid, 256, 0, stream>>>(hs, Wm, bv, cb, out, hist);
    vq_ppl<<<1, 64, 0, stream>>>(hist, out + (size_t)BT * G * Dg);
}

// Round 4
// 192.518 us; speedup vs baseline: 3.2707x; 2.5618x over previous
//
#include <hip/hip_runtime.h>
#include <hip/hip_bf16.h>

// B=16, S=4096, H=512 ; G=2, V=320, D=256 (Dg=128)
constexpr int BT = 65536;
constexpr int K  = 512;
constexpr int V  = 320;
constexpr int G  = 2;
constexpr int Dg = 128;
constexpr int MT = 64;       // rows per block
// ws layout (bytes): [0,2560) hist ; Wh_t bf16[640][512] @4096 ; Wl_t after it
constexpr size_t WS_WH = 4096;
constexpr size_t WS_WL = 4096 + (size_t)640 * 512 * 2;

using short8 = __attribute__((ext_vector_type(8))) short;
using f32x4  = __attribute__((ext_vector_type(4))) float;

static __device__ __forceinline__ unsigned short f2bf(float x) {
    unsigned u = __float_as_uint(x);
    unsigned r = 0x7FFFu + ((u >> 16) & 1u);   // RNE
    return (unsigned short)((u + r) >> 16);
}
static __device__ __forceinline__ float bf2f(unsigned short h) {
    return __uint_as_float(((unsigned)h) << 16);
}
static __device__ __forceinline__ f32x4 mfma16(short8 a, short8 b, f32x4 c) {
    return __builtin_amdgcn_mfma_f32_16x16x32_bf16(a, b, c, 0, 0, 0);
}

// ---- prep: split W (512,640) fp32 into hi/lo bf16, TRANSPOSED to [gc][k] ----
__global__ __launch_bounds__(256) void vq_prep(const float* __restrict__ Wm,
                                               unsigned short* __restrict__ wh,
                                               unsigned short* __restrict__ wl)
{
    int id = blockIdx.x * 256 + threadIdx.x;   // 0..327679 ; k major for coalesced reads
    int k  = id / 640;
    int gc = id - k * 640;
    float x = Wm[(size_t)k * 640 + gc];
    unsigned short h = f2bf(x);
    unsigned short l = f2bf(x - bf2f(h));
    wh[(size_t)gc * 512 + k] = h;
    wl[(size_t)gc * 512 + k] = l;
}

// ---- main: fused split-bf16 MFMA GEMM (64 x 320 x 512) + argmax + gather + hist ----
// grid: 2048 blocks, g = bid&1 (consecutive blocks share hs panel -> L2 hit)
// 4 waves, wave wc covers rows 0..63 x cols wc*80..wc*80+79 (4 mt x 5 nt tiles)
__global__ __launch_bounds__(256) void vq_main(
    const float* __restrict__ hs, const unsigned short* __restrict__ wh,
    const unsigned short* __restrict__ wl, const float* __restrict__ bv,
    const float* __restrict__ cbv, float* __restrict__ out,
    unsigned int* __restrict__ hist)
{
    // LDS: Ah[64][32]bf16 @0 (4 KB), Al @4096, Bh[320][32]bf16 @8192 (20 KB), Bl @28672
    __shared__ __align__(16) unsigned char smem[49152];

    const int tid  = threadIdx.x;
    const int bid  = blockIdx.x;
    const int g    = bid & 1;
    const int r0   = (bid >> 1) * MT;
    const int wc   = tid >> 6;      // wave id = col quarter
    const int lane = tid & 63;
    const int l4   = lane & 15;
    const int lc   = lane >> 4;     // k-chunk (8 bf16 each)

    f32x4 acc[4][5] = {};           // [mt][nt], zero-init; bias added at epilogue

    // frag read byte offsets (swizzle masks derived from addr bits above XOR range -> bijective)
    const int a_base = ((l4 * 64) + lc * 16) ^ (((lane >> 1) & 3) << 4);           // + mt*1024 (+4096 for Al)
    const int b_base = ((wc * 80 + l4) * 64 + lc * 16) ^ (((lane >> 1) & 7) << 4); // + nt*1024

    // A staging map: idx = i*256+tid -> row = idx>>3, q4 = idx&7 (float4 of 4 k)
    // B staging map: idx = i*256+tid (0..2559): <1280 -> Bh, else Bl; j>>2 = col, j&3 = 16B chunk

    for (int kt = 0; kt < K; kt += 32) {
        // ---- stage A: 64x32 fp32 -> hi/lo bf16 (2 float4 per thread) ----
#pragma unroll
        for (int i = 0; i < 2; ++i) {
            int idx = i * 256 + tid;
            int row = idx >> 3;
            int q4  = idx & 7;
            float4 h4 = *reinterpret_cast<const float4*>(&hs[(size_t)(r0 + row) * K + kt + q4 * 4]);
            unsigned short h0 = f2bf(h4.x), h1 = f2bf(h4.y), h2 = f2bf(h4.z), h3 = f2bf(h4.w);
            unsigned short l0 = f2bf(h4.x - bf2f(h0)), l1 = f2bf(h4.y - bf2f(h1));
            unsigned short l2 = f2bf(h4.z - bf2f(h2)), l3 = f2bf(h4.w - bf2f(h3));
            int off = (row * 64 + q4 * 8) ^ (((row >> 1) & 3) << 4);
            uint2 hv; hv.x = (unsigned)h0 | ((unsigned)h1 << 16); hv.y = (unsigned)h2 | ((unsigned)h3 << 16);
            uint2 lv; lv.x = (unsigned)l0 | ((unsigned)l1 << 16); lv.y = (unsigned)l2 | ((unsigned)l3 << 16);
            *reinterpret_cast<uint2*>(smem + off)        = hv;
            *reinterpret_cast<uint2*>(smem + 4096 + off) = lv;
        }
        // ---- stage B: Wh/Wl panels [320][32] bf16, transposed layout, 10x16B per thread ----
#pragma unroll
        for (int i = 0; i < 10; ++i) {
            int idx  = i * 256 + tid;           // 0..2559
            int hsel = (idx >= 1280) ? 1 : 0;
            int j    = idx - hsel * 1280;
            int c    = j >> 2;
            int q    = j & 3;
            const unsigned short* src = (hsel ? wl : wh) + ((size_t)(g * V + c) * K + kt + q * 8);
            uint4 w = *reinterpret_cast<const uint4*>(src);
            int off = (hsel ? 28672 : 8192) + ((c * 64 + q * 16) ^ (((c >> 1) & 7) << 4));
            *reinterpret_cast<uint4*>(smem + off) = w;
        }
        __syncthreads();
        // ---- compute: 8 A-frag reads + 10 B-frag reads, 60 MFMA ----
        short8 ah[4], al[4];
#pragma unroll
        for (int mt = 0; mt < 4; ++mt) {
            ah[mt] = *reinterpret_cast<const short8*>(smem + (a_base + mt * 1024));
            al[mt] = *reinterpret_cast<const short8*>(smem + 4096 + (a_base + mt * 1024));
        }
#pragma unroll
        for (int nt = 0; nt < 5; ++nt) {
            short8 bh = *reinterpret_cast<const short8*>(smem + 8192  + (b_base + nt * 1024));
            short8 bl = *reinterpret_cast<const short8*>(smem + 28672 + (b_base + nt * 1024));
#pragma unroll
            for (int mt = 0; mt < 4; ++mt) acc[mt][nt] = mfma16(ah[mt], bh, acc[mt][nt]);
#pragma unroll
            for (int mt = 0; mt < 4; ++mt) acc[mt][nt] = mfma16(al[mt], bh, acc[mt][nt]);
#pragma unroll
            for (int mt = 0; mt < 4; ++mt) acc[mt][nt] = mfma16(ah[mt], bl, acc[mt][nt]);
        }
        __syncthreads();
    }

    // ---- epilogue: bias + argmax ----
    // D layout: col = l4 (within nt tile), row = lc*4 + reg (within mt tile)
    float biasv[5];
#pragma unroll
    for (int nt = 0; nt < 5; ++nt) biasv[nt] = bv[g * V + wc * 80 + nt * 16 + l4];

    float* red_v = reinterpret_cast<float*>(smem);          // [64][4]
    int*   red_i = reinterpret_cast<int*>(smem + 1024);     // [64][4]
    int*   idx_s = reinterpret_cast<int*>(smem + 2048);     // [64]

#pragma unroll
    for (int mt = 0; mt < 4; ++mt) {
#pragma unroll
        for (int reg = 0; reg < 4; ++reg) {
            float bestv = acc[mt][0][reg] + biasv[0];
            int   besti = wc * 80 + l4;
#pragma unroll
            for (int nt = 1; nt < 5; ++nt) {
                float v = acc[mt][nt][reg] + biasv[nt];
                int   ci = wc * 80 + nt * 16 + l4;
                if (v > bestv) { bestv = v; besti = ci; }
            }
            // butterfly over the 16-lane group holding this row (max, min-index tie-break)
#pragma unroll
            for (int m = 1; m < 16; m <<= 1) {
                float ov = __shfl_xor(bestv, m);
                int   oi = __shfl_xor(besti, m);
                if (ov > bestv || (ov == bestv && oi < besti)) { bestv = ov; besti = oi; }
            }
            if (l4 == 0) {
                int row = mt * 16 + lc * 4 + reg;
                red_v[row * 4 + wc] = bestv;
                red_i[row * 4 + wc] = besti;
            }
        }
    }
    __syncthreads();

    if (tid < MT) {
        float bb = red_v[tid * 4]; int bi = red_i[tid * 4];
#pragma unroll
        for (int c = 1; c < 4; ++c) {
            float v = red_v[tid * 4 + c]; int ii = red_i[tid * 4 + c];
            if (v > bb || (v == bb && ii < bi)) { bb = v; bi = ii; }
        }
        idx_s[tid] = bi;
        atomicAdd(&hist[g * V + bi], 1u);
    }
    __syncthreads();

    // ---- gather: 64 rows x 32 float4, 8 per thread ----
#pragma unroll
    for (int i = 0; i < 8; ++i) {
        int idx = i * 256 + tid;
        int row = idx >> 5;
        int d4  = idx & 31;
        int vi  = idx_s[row];
        float4 val = *reinterpret_cast<const float4*>(&cbv[((size_t)(g * V + vi)) * Dg + d4 * 4]);
        *reinterpret_cast<float4*>(&out[((size_t)(r0 + row)) * (G * Dg) + g * Dg + d4 * 4]) = val;
    }
}

// Perplexity from histogram: one wave.
__global__ void vq_ppl(const unsigned int* __restrict__ hist, float* __restrict__ outp)
{
    int lane = threadIdx.x;  // 64
    float ppl = 0.0f;
    for (int g = 0; g < G; ++g) {
        float local = 0.0f;
        for (int v = lane; v < V; v += 64) {
            float m = (float)hist[g * V + v] * (1.0f / (float)BT);
            local += m * logf(m + 1e-7f);
        }
#pragma unroll
        for (int off = 32; off; off >>= 1) local += __shfl_down(local, off);
        if (lane == 0) ppl += expf(-local);
    }
    if (lane == 0) outp[0] = ppl;
}

extern "C" void kernel_launch(void* const* d_in, const int* in_sizes, int n_in,
                              void* d_out, int out_size, void* d_ws, size_t ws_size,
                              hipStream_t stream)
{
    const float* hs  = (const float*)d_in[0];   // (65536, 512)
    const float* Wm  = (const float*)d_in[1];   // (512, 640)
    const float* bv  = (const float*)d_in[2];   // (640,)
    const float* cbv = (const float*)d_in[3];   // (640, 128)
    float* out = (float*)d_out;                 // 65536*256 floats, then 1 float perplexity

    unsigned int*   hist = (unsigned int*)d_ws;
    unsigned short* wh   = (unsigned short*)((char*)d_ws + WS_WH);
    unsigned short* wl   = (unsigned short*)((char*)d_ws + WS_WL);

    hipMemsetAsync(d_ws, 0, G * V * sizeof(unsigned int), stream);
    vq_prep<<<1280, 256, 0, stream>>>(Wm, wh, wl);
    vq_main<<<2048, 256, 0, stream>>>(hs, wh, wl, bv, cbv, out, hist);
    vq_ppl<<<1, 64, 0, stream>>>(hist, out + (size_t)BT * G * Dg);
}

// Round 5
// 141.189 us; speedup vs baseline: 4.4598x; 1.3635x over previous
//
#include <hip/hip_runtime.h>
#include <hip/hip_bf16.h>

// B=16,S=4096,H=512 ; G=2,V=320,D=256 (Dg=128)
constexpr int BT = 65536;
constexpr int K  = 512;
constexpr int V  = 320;
constexpr int G  = 2;
constexpr int Dg = 128;
constexpr int MT = 64;
constexpr int NSTEP = 16;        // K / 32
constexpr int BUFB  = 28672;     // LDS buffer: Ah 4K @0, Al 4K @4096, Bh 20K @8192
// ws: [0,2560) hist ; Bh swizzled LDS-image panels @4096: [g*16+t][20480 bytes]
constexpr size_t WS_IMG = 4096;

using short8 = __attribute__((ext_vector_type(8))) short;
using f32x4  = __attribute__((ext_vector_type(4))) float;

static __device__ __forceinline__ unsigned short f2bf(float x) {
    unsigned u = __float_as_uint(x);
    unsigned r = 0x7FFFu + ((u >> 16) & 1u);   // RNE
    return (unsigned short)((u + r) >> 16);
}
static __device__ __forceinline__ float bf2f(unsigned short h) {
    return __uint_as_float(((unsigned)h) << 16);
}
static __device__ __forceinline__ f32x4 mfma16(short8 a, short8 b, f32x4 c) {
    return __builtin_amdgcn_mfma_f32_16x16x32_bf16(a, b, c, 0, 0, 0);
}

// ---- prep: build swizzled LDS byte-images of the Bh panels ----
// img[(g*16+t)*20480 + ((c*64+q*16) ^ (((c>>1)&7)<<4))] = bf16x8 of W[t*32+q*8 .. +7][g*320+c]
__global__ __launch_bounds__(256) void vq_prep(const float* __restrict__ Wm,
                                               unsigned char* __restrict__ img)
{
    int id = blockIdx.x * 256 + threadIdx.x;   // 0..40959 chunks (grid 160*256 exact)
    int q  = id & 3;
    int c  = (id >> 2) % V;
    int tk = (id >> 2) / V;                    // g*16 + t
    int g  = tk >> 4;
    int t  = tk & 15;
    int kb = t * 32 + q * 8;
    unsigned int p[4];
#pragma unroll
    for (int jj = 0; jj < 4; ++jj) {
        unsigned short h0 = f2bf(Wm[(size_t)(kb + jj * 2    ) * 640 + g * V + c]);
        unsigned short h1 = f2bf(Wm[(size_t)(kb + jj * 2 + 1) * 640 + g * V + c]);
        p[jj] = (unsigned)h0 | ((unsigned)h1 << 16);
    }
    *reinterpret_cast<uint4*>(img + (size_t)tk * 20480 +
        ((c * 64 + q * 16) ^ (((c >> 1) & 7) << 4))) = make_uint4(p[0], p[1], p[2], p[3]);
}

// ---- main: C = (Ah+Al)*Bh (exact-A x bf16-B), double-buffered 2-phase pipeline ----
// grid 2048: g = (bid>>3)&1, rblk = (bid&7)|((bid>>4)<<3)  (bid, bid+8 share hs panel -> same-XCD L2 hit)
__global__ __launch_bounds__(256) void vq_main(
    const float* __restrict__ hs, const unsigned char* __restrict__ img,
    const float* __restrict__ bv, const float* __restrict__ cbv,
    float* __restrict__ out, unsigned int* __restrict__ hist)
{
    __shared__ __align__(16) unsigned char smem[2 * BUFB];   // 56 KB -> 2 blocks/CU

    const int tid  = threadIdx.x;
    const int bid  = blockIdx.x;
    const int g    = (bid >> 3) & 1;
    const int rblk = (bid & 7) | ((bid >> 4) << 3);
    const int r0   = rblk * MT;
    const int wc   = tid >> 6;      // wave id = col quarter
    const int lane = tid & 63;
    const int l4   = lane & 15;
    const int lc   = lane >> 4;

    f32x4 acc[4][5] = {};

    const int a_base = ((l4 * 64) + lc * 16) ^ (((lane >> 1) & 3) << 4);
    const int b_base = ((wc * 80 + l4) * 64 + lc * 16) ^ (((lane >> 1) & 7) << 4);

    // A staging map (2 float4/thread): idx = i*256+tid -> row = idx>>3, q4 = idx&7
    const int arow0 = tid >> 3;
    const int aq0   = tid & 7;
    const int arow1 = (256 + tid) >> 3;
    const int aq1   = (256 + tid) & 7;
    const int awoff0 = (arow0 * 64 + aq0 * 8) ^ (((arow0 >> 1) & 3) << 4);
    const int awoff1 = (arow1 * 64 + aq1 * 8) ^ (((arow1 >> 1) & 3) << 4);
    const float* aptr0 = hs + (size_t)(r0 + arow0) * K + aq0 * 4;
    const float* aptr1 = hs + (size_t)(r0 + arow1) * K + aq1 * 4;
    // B image source for this wave (lane*16 folded in; 5 chunks of 1KB per wave)
    const unsigned char* bsrc = img + (size_t)(g * 16) * 20480 + (wc * 5) * 1024 + lane * 16;

    auto stageB = [&](int t, int boff) {
#pragma unroll
        for (int i = 0; i < 5; ++i) {
            __builtin_amdgcn_global_load_lds(
                (const __attribute__((address_space(1))) void*)(bsrc + (size_t)t * 20480 + i * 1024),
                (__attribute__((address_space(3))) void*)(&smem[boff + 8192 + (wc * 5 + i) * 1024]),
                16, 0, 0);
        }
    };
    auto writeA = [&](float4 v, int off, int boff) {
        unsigned short h0 = f2bf(v.x), h1 = f2bf(v.y), h2 = f2bf(v.z), h3 = f2bf(v.w);
        unsigned short l0 = f2bf(v.x - bf2f(h0)), l1 = f2bf(v.y - bf2f(h1));
        unsigned short l2 = f2bf(v.z - bf2f(h2)), l3 = f2bf(v.w - bf2f(h3));
        uint2 hv; hv.x = (unsigned)h0 | ((unsigned)h1 << 16); hv.y = (unsigned)h2 | ((unsigned)h3 << 16);
        uint2 lv; lv.x = (unsigned)l0 | ((unsigned)l1 << 16); lv.y = (unsigned)l2 | ((unsigned)l3 << 16);
        *reinterpret_cast<uint2*>(&smem[boff + off])        = hv;
        *reinterpret_cast<uint2*>(&smem[boff + 4096 + off]) = lv;
    };

    // prologue: stage tile 0 into buffer 0
    {
        float4 a0 = *reinterpret_cast<const float4*>(aptr0);
        float4 a1 = *reinterpret_cast<const float4*>(aptr1);
        stageB(0, 0);
        writeA(a0, awoff0, 0);
        writeA(a1, awoff1, 0);
    }
    __syncthreads();

    int cur = 0;
#pragma unroll 2
    for (int t = 0; t < NSTEP; ++t) {
        const int curoff = cur * BUFB;
        const int nxtoff = curoff ^ BUFB;
        float4 a0, a1;
        if (t + 1 < NSTEP) {
            a0 = *reinterpret_cast<const float4*>(aptr0 + (t + 1) * 32);
            a1 = *reinterpret_cast<const float4*>(aptr1 + (t + 1) * 32);
            stageB(t + 1, nxtoff);
        }
        // compute tile t: 13 ds_read_b128 + 40 MFMA per wave
        short8 ah[4], al[4];
#pragma unroll
        for (int mt = 0; mt < 4; ++mt) {
            ah[mt] = *reinterpret_cast<const short8*>(&smem[curoff + a_base + mt * 1024]);
            al[mt] = *reinterpret_cast<const short8*>(&smem[curoff + 4096 + a_base + mt * 1024]);
        }
#pragma unroll
        for (int nt = 0; nt < 5; ++nt) {
            short8 bh = *reinterpret_cast<const short8*>(&smem[curoff + 8192 + b_base + nt * 1024]);
#pragma unroll
            for (int mt = 0; mt < 4; ++mt) acc[mt][nt] = mfma16(ah[mt], bh, acc[mt][nt]);
#pragma unroll
            for (int mt = 0; mt < 4; ++mt) acc[mt][nt] = mfma16(al[mt], bh, acc[mt][nt]);
        }
        if (t + 1 < NSTEP) {
            writeA(a0, awoff0, nxtoff);   // vmcnt wait inserted here by compiler; hid under MFMA
            writeA(a1, awoff1, nxtoff);
        }
        __syncthreads();
        cur ^= 1;
    }

    // ---- epilogue: bias + argmax (D layout: col=l4, row=lc*4+reg within 16x16 tile) ----
    float biasv[5];
#pragma unroll
    for (int nt = 0; nt < 5; ++nt) biasv[nt] = bv[g * V + wc * 80 + nt * 16 + l4];

    float* red_v = reinterpret_cast<float*>(smem);          // [64][4]
    int*   red_i = reinterpret_cast<int*>(smem + 1024);     // [64][4]
    int*   idx_s = reinterpret_cast<int*>(smem + 2048);     // [64]

#pragma unroll
    for (int mt = 0; mt < 4; ++mt) {
#pragma unroll
        for (int reg = 0; reg < 4; ++reg) {
            float bestv = acc[mt][0][reg] + biasv[0];
            int   besti = wc * 80 + l4;
#pragma unroll
            for (int nt = 1; nt < 5; ++nt) {
                float v = acc[mt][nt][reg] + biasv[nt];
                int   ci = wc * 80 + nt * 16 + l4;
                if (v > bestv) { bestv = v; besti = ci; }
            }
#pragma unroll
            for (int m = 1; m < 16; m <<= 1) {
                float ov = __shfl_xor(bestv, m);
                int   oi = __shfl_xor(besti, m);
                if (ov > bestv || (ov == bestv && oi < besti)) { bestv = ov; besti = oi; }
            }
            if (l4 == 0) {
                int row = mt * 16 + lc * 4 + reg;
                red_v[row * 4 + wc] = bestv;
                red_i[row * 4 + wc] = besti;
            }
        }
    }
    __syncthreads();

    if (tid < MT) {
        float bb = red_v[tid * 4]; int bi = red_i[tid * 4];
#pragma unroll
        for (int c = 1; c < 4; ++c) {
            float v = red_v[tid * 4 + c]; int ii = red_i[tid * 4 + c];
            if (v > bb || (v == bb && ii < bi)) { bb = v; bi = ii; }
        }
        idx_s[tid] = bi;
        atomicAdd(&hist[g * V + bi], 1u);
    }
    __syncthreads();

    // ---- gather: 64 rows x 32 float4, 8 per thread ----
#pragma unroll
    for (int i = 0; i < 8; ++i) {
        int idx = i * 256 + tid;
        int row = idx >> 5;
        int d4  = idx & 31;
        int vi  = idx_s[row];
        float4 val = *reinterpret_cast<const float4*>(&cbv[((size_t)(g * V + vi)) * Dg + d4 * 4]);
        *reinterpret_cast<float4*>(&out[((size_t)(r0 + row)) * (G * Dg) + g * Dg + d4 * 4]) = val;
    }
}

// Perplexity from histogram: one wave.
__global__ void vq_ppl(const unsigned int* __restrict__ hist, float* __restrict__ outp)
{
    int lane = threadIdx.x;  // 64
    float ppl = 0.0f;
    for (int g = 0; g < G; ++g) {
        float local = 0.0f;
        for (int v = lane; v < V; v += 64) {
            float m = (float)hist[g * V + v] * (1.0f / (float)BT);
            local += m * logf(m + 1e-7f);
        }
#pragma unroll
        for (int off = 32; off; off >>= 1) local += __shfl_down(local, off);
        if (lane == 0) ppl += expf(-local);
    }
    if (lane == 0) outp[0] = ppl;
}

extern "C" void kernel_launch(void* const* d_in, const int* in_sizes, int n_in,
                              void* d_out, int out_size, void* d_ws, size_t ws_size,
                              hipStream_t stream)
{
    const float* hs  = (const float*)d_in[0];   // (65536, 512)
    const float* Wm  = (const float*)d_in[1];   // (512, 640)
    const float* bv  = (const float*)d_in[2];   // (640,)
    const float* cbv = (const float*)d_in[3];   // (640, 128)
    float* out = (float*)d_out;                 // 65536*256 floats + 1 float perplexity

    unsigned int*  hist = (unsigned int*)d_ws;
    unsigned char* img  = (unsigned char*)d_ws + WS_IMG;

    hipMemsetAsync(d_ws, 0, G * V * sizeof(unsigned int), stream);
    vq_prep<<<160, 256, 0, stream>>>(Wm, img);
    vq_main<<<2048, 256, 0, stream>>>(hs, img, bv, cbv, out, hist);
    vq_ppl<<<1, 64, 0, stream>>>(hist, out + (size_t)BT * G * Dg);
}

// Round 6
// 106.717 us; speedup vs baseline: 5.9004x; 1.3230x over previous
//
#include <hip/hip_runtime.h>
#include <hip/hip_bf16.h>

// B=16,S=4096,H=512 ; G=2,V=320,D=256 (Dg=128)
constexpr int BT = 65536;
constexpr int K  = 512;
constexpr int V  = 320;
constexpr int G  = 2;
constexpr int Dg = 128;
constexpr int MT = 64;
constexpr int NSTEP = 16;        // K/32
// ws: [0,2560) hist ; fragment-ordered B img @4096 (640 KB)
constexpr size_t WS_IMG = 4096;

using short8 = __attribute__((ext_vector_type(8))) short;
using f32x4  = __attribute__((ext_vector_type(4))) float;

static __device__ __forceinline__ unsigned short f2bf(float x) {
    unsigned u = __float_as_uint(x);
    unsigned r = 0x7FFFu + ((u >> 16) & 1u);   // RNE
    return (unsigned short)((u + r) >> 16);
}
static __device__ __forceinline__ unsigned pk2(float a, float b) {
    return (unsigned)f2bf(a) | ((unsigned)f2bf(b) << 16);
}
static __device__ __forceinline__ f32x4 mfma16(short8 a, short8 b, f32x4 c) {
    return __builtin_amdgcn_mfma_f32_16x16x32_bf16(a, b, c, 0, 0, 0);
}

// ---- prep: fragment-ordered bf16 B image ----
// chunk index = (((g*16+t)*4+wc)*5+nt)*64+lane, 16 bytes each.
// chunk data = bf16 of W[t*32+(lane>>4)*8 .. +7][g*320 + wc*80+nt*16+(lane&15)]
__global__ __launch_bounds__(256) void vq_prep(const float* __restrict__ Wm,
                                               unsigned char* __restrict__ img)
{
    int id   = blockIdx.x * 256 + threadIdx.x;   // 0..40959
    int lane = id & 63;
    int s    = id >> 6;        // (((g*16+t)*4+wc)*5+nt)
    int nt   = s % 5;
    int wcq  = (s / 5) & 3;
    int tk   = s / 20;         // g*16+t
    int g    = tk >> 4;
    int t    = tk & 15;
    int col  = g * V + wcq * 80 + nt * 16 + (lane & 15);
    int kb   = t * 32 + (lane >> 4) * 8;
    unsigned p[4];
#pragma unroll
    for (int jj = 0; jj < 4; ++jj)
        p[jj] = pk2(Wm[(size_t)(kb + 2 * jj) * 640 + col],
                    Wm[(size_t)(kb + 2 * jj + 1) * 640 + col]);
    *reinterpret_cast<uint4*>(img + (size_t)id * 16) = make_uint4(p[0], p[1], p[2], p[3]);
}

// ---- main: bf16 MFMA GEMM (64x320x512), B in registers, A via 8KB LDS dbuf ----
// grid 2048: g=(bid>>3)&1, rblk=(bid&7)|((bid>>4)<<3)  (bid,bid+8 same XCD share hs)
__global__ __launch_bounds__(256) void vq_main(
    const float* __restrict__ hs, const unsigned char* __restrict__ img,
    const float* __restrict__ bv, const float* __restrict__ cbv,
    float* __restrict__ out, unsigned int* __restrict__ hist)
{
    __shared__ __align__(16) unsigned char smem[8192];   // A: [2][64 rows][32 k] bf16

    const int tid  = threadIdx.x;
    const int bid  = blockIdx.x;
    const int g    = (bid >> 3) & 1;
    const int rblk = (bid & 7) | ((bid >> 4) << 3);
    const int r0   = rblk * MT;
    const int wc   = tid >> 6;
    const int lane = tid & 63;
    const int l4   = lane & 15;
    const int lc   = lane >> 4;

    f32x4 acc[4][5] = {};

    // A staging: thread tid stages 8 floats of row (tid>>2), k-chunk (tid&3)
    const float* aptr = hs + (size_t)(r0 + (tid >> 2)) * K + (tid & 3) * 8;
    const int    awoff = tid * 16;                      // linear 4KB panel
    // A fragment read: contiguous 1KB per (wave,mt) -> conflict-free, no swizzle
    const int a_off = l4 * 64 + lc * 16;                // + mt*1024 + buf*4096
    // B source for this (g,wc,lane)
    const unsigned char* bsrc = img + (size_t)g * 327680 + wc * 5120 + lane * 16;

    auto bload = [&](int t, int nt) {
        return *reinterpret_cast<const short8*>(bsrc + (size_t)t * 20480 + nt * 1024);
    };
    auto packA = [&](float4 x, float4 y, int boff) {
        *reinterpret_cast<uint4*>(&smem[boff + awoff]) =
            make_uint4(pk2(x.x, x.y), pk2(x.z, x.w), pk2(y.x, y.y), pk2(y.z, y.w));
    };

    short8 breg[2][5];
    float4 aX[2], aY[2];

    // ---- prologue ----
    aX[0] = *reinterpret_cast<const float4*>(aptr);            // A(0)
    aY[0] = *reinterpret_cast<const float4*>(aptr + 4);
#pragma unroll
    for (int nt = 0; nt < 5; ++nt) breg[0][nt] = bload(0, nt); // B(0)
    packA(aX[0], aY[0], 0);                                    // write A(0) -> buf0
    aX[1] = *reinterpret_cast<const float4*>(aptr + 32);       // A(1) in flight
    aY[1] = *reinterpret_cast<const float4*>(aptr + 36);
    asm volatile("s_waitcnt lgkmcnt(0)" ::: "memory");
    __builtin_amdgcn_sched_barrier(0);
    __builtin_amdgcn_s_barrier();

#pragma unroll
    for (int t = 0; t < NSTEP; ++t) {
        const int cur = t & 1, nxt = cur ^ 1;
        // issue B(t+1) -> regs (stays in flight across the raw barrier: no vmcnt drain)
        if (t + 1 < NSTEP) {
#pragma unroll
            for (int nt = 0; nt < 5; ++nt) breg[nxt][nt] = bload(t + 1, nt);
        }
        // issue A(t+2) -> regs (2-step-ahead HBM prefetch)
        if (t + 2 < NSTEP) {
            aX[cur] = *reinterpret_cast<const float4*>(aptr + (t + 2) * 32);
            aY[cur] = *reinterpret_cast<const float4*>(aptr + (t + 2) * 32 + 4);
        }
        // A fragments from LDS[cur]
        short8 ah[4];
#pragma unroll
        for (int mt = 0; mt < 4; ++mt)
            ah[mt] = *reinterpret_cast<const short8*>(&smem[cur * 4096 + a_off + mt * 1024]);
        // 20 MFMA
#pragma unroll
        for (int nt = 0; nt < 5; ++nt)
#pragma unroll
            for (int mt = 0; mt < 4; ++mt)
                acc[mt][nt] = mfma16(ah[mt], breg[cur][nt], acc[mt][nt]);
        // convert+write A(t+1) into LDS[nxt]
        if (t + 1 < NSTEP) packA(aX[nxt], aY[nxt], nxt * 4096);
        // write-side drain + raw barrier (B loads remain in flight)
        asm volatile("s_waitcnt lgkmcnt(0)" ::: "memory");
        __builtin_amdgcn_sched_barrier(0);
        __builtin_amdgcn_s_barrier();
    }

    // ---- epilogue: bias + argmax (D layout: col=l4, row=lc*4+reg in 16x16 tile) ----
    float biasv[5];
#pragma unroll
    for (int nt = 0; nt < 5; ++nt) biasv[nt] = bv[g * V + wc * 80 + nt * 16 + l4];

    float* red_v = reinterpret_cast<float*>(smem);          // [64][4]
    int*   red_i = reinterpret_cast<int*>(smem + 1024);     // [64][4]
    int*   idx_s = reinterpret_cast<int*>(smem + 2048);     // [64]

#pragma unroll
    for (int mt = 0; mt < 4; ++mt) {
#pragma unroll
        for (int reg = 0; reg < 4; ++reg) {
            float bestv = acc[mt][0][reg] + biasv[0];
            int   besti = wc * 80 + l4;
#pragma unroll
            for (int nt = 1; nt < 5; ++nt) {
                float v = acc[mt][nt][reg] + biasv[nt];
                int   ci = wc * 80 + nt * 16 + l4;
                if (v > bestv) { bestv = v; besti = ci; }
            }
#pragma unroll
            for (int m = 1; m < 16; m <<= 1) {
                float ov = __shfl_xor(bestv, m);
                int   oi = __shfl_xor(besti, m);
                if (ov > bestv || (ov == bestv && oi < besti)) { bestv = ov; besti = oi; }
            }
            if (l4 == 0) {
                int row = mt * 16 + lc * 4 + reg;
                red_v[row * 4 + wc] = bestv;
                red_i[row * 4 + wc] = besti;
            }
        }
    }
    __syncthreads();

    if (tid < MT) {
        float bb = red_v[tid * 4]; int bi = red_i[tid * 4];
#pragma unroll
        for (int c = 1; c < 4; ++c) {
            float v = red_v[tid * 4 + c]; int ii = red_i[tid * 4 + c];
            if (v > bb || (v == bb && ii < bi)) { bb = v; bi = ii; }
        }
        idx_s[tid] = bi;
        atomicAdd(&hist[g * V + bi], 1u);
    }
    __syncthreads();

    // ---- gather: 64 rows x 32 float4, 8 per thread ----
#pragma unroll
    for (int i = 0; i < 8; ++i) {
        int idx = i * 256 + tid;
        int row = idx >> 5;
        int d4  = idx & 31;
        int vi  = idx_s[row];
        float4 val = *reinterpret_cast<const float4*>(&cbv[((size_t)(g * V + vi)) * Dg + d4 * 4]);
        *reinterpret_cast<float4*>(&out[((size_t)(r0 + row)) * (G * Dg) + g * Dg + d4 * 4]) = val;
    }
}

// Perplexity from histogram: one wave.
__global__ void vq_ppl(const unsigned int* __restrict__ hist, float* __restrict__ outp)
{
    int lane = threadIdx.x;  // 64
    float ppl = 0.0f;
    for (int g = 0; g < G; ++g) {
        float local = 0.0f;
        for (int v = lane; v < V; v += 64) {
            float m = (float)hist[g * V + v] * (1.0f / (float)BT);
            local += m * logf(m + 1e-7f);
        }
#pragma unroll
        for (int off = 32; off; off >>= 1) local += __shfl_down(local, off);
        if (lane == 0) ppl += expf(-local);
    }
    if (lane == 0) outp[0] = ppl;
}

extern "C" void kernel_launch(void* const* d_in, const int* in_sizes, int n_in,
                              void* d_out, int out_size, void* d_ws, size_t ws_size,
                              hipStream_t stream)
{
    const float* hs  = (const float*)d_in[0];   // (65536, 512)
    const float* Wm  = (const float*)d_in[1];   // (512, 640)
    const float* bv  = (const float*)d_in[2];   // (640,)
    const float* cbv = (const float*)d_in[3];   // (640, 128)
    float* out = (float*)d_out;                 // 65536*256 floats + 1 float perplexity

    unsigned int*  hist = (unsigned int*)d_ws;
    unsigned char* img  = (unsigned char*)d_ws + WS_IMG;

    hipMemsetAsync(d_ws, 0, G * V * sizeof(unsigned int), stream);
    vq_prep<<<160, 256, 0, stream>>>(Wm, img);
    vq_main<<<2048, 256, 0, stream>>>(hs, img, bv, cbv, out, hist);
    vq_ppl<<<1, 64, 0, stream>>>(hist, out + (size_t)BT * G * Dg);
}